// Round 7
// baseline (117.914 us; speedup 1.0000x reference)
//
#include <hip/hip_runtime.h>
#include <math.h>

typedef __attribute__((ext_vector_type(8))) short short8;
typedef __attribute__((ext_vector_type(8))) _Float16 f16x8;
typedef __attribute__((ext_vector_type(4))) float floatx4;
typedef __attribute__((ext_vector_type(16))) float floatx16;

#define B_ROWS 8192
#define FIN    512
#define FOUT   512

// ---- workspace byte offsets ----
#define WSB_SW   0UL         // 8 floats
#define WSB_CNT  64UL        // 8192 int (any-NaN flag per row)
#define WSB_BASE 65536UL     // 8192*512 f16 base GEMM result
#define WSB_XCH  16842752UL  // 8192*512 f16 cleaned x
#define WSB_MSK  25231360UL  // 8192*512 f16 mask (1.0/0.0)
#define WSB_WH   33619968UL  // 512*512 f16 W [o][f]
#define WSB_BCT  34144256UL  // 8192*512 f16 BcT[n=o*16+t][f]

__device__ __forceinline__ void gl2lds16(const void* g, void* l) {
    __builtin_amdgcn_global_load_lds((const __attribute__((address_space(1))) void*)g,
                                     (__attribute__((address_space(3))) void*)l,
                                     16, 0, 0);
}

__device__ __forceinline__ float frcp(float x) { float r; asm("v_rcp_f32 %0, %1" : "=v"(r) : "v"(x)); return r; }
__device__ __forceinline__ float frsq(float x) { float r; asm("v_rsq_f32 %0, %1" : "=v"(r) : "v"(x)); return r; }
__device__ __forceinline__ float fexp2(float x){ float r; asm("v_exp_f32 %0, %1" : "=v"(r) : "v"(x)); return r; }

// ---------------- prep: BcT[n][f] (n=o*16+t) + Wh fold ----------------
__global__ __launch_bounds__(256) void prep_bct(const float* __restrict__ W,
                                                const float* __restrict__ mean_p,
                                                const float* __restrict__ ls2,
                                                _Float16* __restrict__ bct,
                                                _Float16* __restrict__ Wh) {
    int tid = threadIdx.x;
    int n  = blockIdx.x * 4 + (tid >> 6);
    int fc = (tid & 63) << 3;
    int o = n >> 4, t = n & 15;
    const float* wp = W + (size_t)o * FIN + fc;
    f16x8 hv;
    if (t < 8) {
        const float* mp = mean_p + (size_t)t * FIN + fc;
#pragma unroll
        for (int j = 0; j < 8; ++j) hv[j] = (_Float16)(mp[j] * wp[j]);
        if (t == 0) {
            f16x8 wv;
#pragma unroll
            for (int j = 0; j < 8; ++j) wv[j] = (_Float16)wp[j];
            *(f16x8*)(Wh + (size_t)o * FIN + fc) = wv;
        }
    } else {
        const float* lp = ls2 + (size_t)(t - 8) * FIN + fc;
#pragma unroll
        for (int j = 0; j < 8; ++j) hv[j] = (_Float16)(expf(lp[j]) * wp[j] * wp[j]);
    }
    *(f16x8*)(bct + (size_t)n * FIN + fc) = hv;
}

// ---------------- prep: cleaned x f16 + mask f16 + any-NaN flag + softmax ----------------
__global__ __launch_bounds__(256) void prep_rows(const float* __restrict__ x,
                                                 _Float16* __restrict__ xch,
                                                 _Float16* __restrict__ msk,
                                                 int* __restrict__ cnts,
                                                 const float* __restrict__ lw,
                                                 float* __restrict__ wsf) {
    int tid = threadIdx.x, lane = tid & 63, wid = tid >> 6;
    int row = blockIdx.x * 4 + wid;
    const float* xr = x + (size_t)row * FIN + lane * 8;
    float4 a = *(const float4*)xr;
    float4 b = *(const float4*)(xr + 4);
    float v[8] = {a.x, a.y, a.z, a.w, b.x, b.y, b.z, b.w};
    f16x8 xo, mo;
    bool anyn = false;
#pragma unroll
    for (int j = 0; j < 8; ++j) {
        bool isn = (v[j] != v[j]);
        anyn |= isn;
        xo[j] = (_Float16)(isn ? 0.f : v[j]);
        mo[j] = (_Float16)(isn ? 1.f : 0.f);
    }
    *(f16x8*)(xch + (size_t)row * FIN + lane * 8) = xo;
    *(f16x8*)(msk + (size_t)row * FIN + lane * 8) = mo;
    bool any = __any(anyn);
    if (lane == 0) cnts[row] = any ? 1 : 0;
    if (blockIdx.x == 0 && tid == 0) {
        float mx = lw[0];
        for (int m = 1; m < 8; ++m) mx = fmaxf(mx, lw[m]);
        float e[8]; float s = 0.f;
        for (int m = 0; m < 8; ++m) { e[m] = expf(lw[m] - mx); s += e[m]; }
        for (int m = 0; m < 8; ++m) wsf[m] = e[m] / s;
    }
}

// ---------------- base GEMM: base[b,o] = sum_f xch[b,f]*Wh[o,f] (f16 MFMA, f16 out) ----------------
__global__ __launch_bounds__(256) void gemm_base(const _Float16* __restrict__ xch,
                                                 const _Float16* __restrict__ Wh,
                                                 _Float16* __restrict__ base) {
    __shared__ short As[128 * 64];
    __shared__ short Bs[64 * 64];
    int tid = threadIdx.x, lane = tid & 63, wid = tid >> 6;
    int wr = wid >> 1, wc = wid & 1;
    int bb0 = blockIdx.y * 128;
    int ob0 = blockIdx.x * 64;

    floatx4 acc[4][2];
#pragma unroll
    for (int mi = 0; mi < 4; ++mi)
#pragma unroll
        for (int ni = 0; ni < 2; ++ni) acc[mi][ni] = (floatx4){0.f, 0.f, 0.f, 0.f};

    for (int ks = 0; ks < FIN; ks += 64) {
        __syncthreads();
#pragma unroll
        for (int i = 0; i < 4; ++i) {
            int cid = i * 256 + tid, row = cid >> 3, c = cid & 7;
            short8 v = *(const short8*)((const short*)xch + (((size_t)(bb0 + row)) << 9) + ks + c * 8);
            *(short8*)(&As[row * 64 + ((c ^ (row & 7)) << 3)]) = v;
        }
#pragma unroll
        for (int i = 0; i < 2; ++i) {
            int cid = i * 256 + tid, row = cid >> 3, c = cid & 7;
            short8 v = *(const short8*)((const short*)Wh + (((size_t)(ob0 + row)) << 9) + ks + c * 8);
            *(short8*)(&Bs[row * 64 + ((c ^ (row & 7)) << 3)]) = v;
        }
        __syncthreads();
#pragma unroll
        for (int kk = 0; kk < 2; ++kk) {
            f16x8 av[4], bv[2];
#pragma unroll
            for (int mi = 0; mi < 4; ++mi) {
                int row = wr * 64 + mi * 16 + (lane & 15);
                int c = kk * 4 + (lane >> 4);
                av[mi] = *(const f16x8*)(&As[row * 64 + ((c ^ (row & 7)) << 3)]);
            }
#pragma unroll
            for (int ni = 0; ni < 2; ++ni) {
                int row = wc * 32 + ni * 16 + (lane & 15);
                int c = kk * 4 + (lane >> 4);
                bv[ni] = *(const f16x8*)(&Bs[row * 64 + ((c ^ (row & 7)) << 3)]);
            }
#pragma unroll
            for (int mi = 0; mi < 4; ++mi)
#pragma unroll
                for (int ni = 0; ni < 2; ++ni)
                    acc[mi][ni] = __builtin_amdgcn_mfma_f32_16x16x32_f16(av[mi], bv[ni], acc[mi][ni], 0, 0, 0);
        }
    }
#pragma unroll
    for (int mi = 0; mi < 4; ++mi)
#pragma unroll
        for (int ni = 0; ni < 2; ++ni)
#pragma unroll
            for (int r = 0; r < 4; ++r) {
                int row = bb0 + wr * 64 + mi * 16 + (lane >> 4) * 4 + r;
                int col = ob0 + wc * 32 + ni * 16 + (lane & 15);
                base[(size_t)row * FOUT + col] = (_Float16)acc[mi][ni][r];
            }
}

// ---------------- fused mask-GEMM + epilogue (32x32x16 MFMA) ----------------
// C[b, n=o*16+t] = sum_f mask[b,f] * BcT[n,f]
// block 256(M) x 128(N), 4 waves (2x2), wave tile 128x64, BK=32,
// 3 x 24KB LDS buffers, depth-2 counted vmcnt, addressing hoisted.
__global__ __launch_bounds__(256, 2) void gmm_fused(const _Float16* __restrict__ msk,
                                                    const _Float16* __restrict__ bct,
                                                    const float* __restrict__ wsf,
                                                    const int* __restrict__ cnts,
                                                    const _Float16* __restrict__ baseh,
                                                    const float* __restrict__ bias,
                                                    float* __restrict__ out) {
    __shared__ char lds[73728];   // 3 x (A 16KB + B 8KB)

    int tid = threadIdx.x, lane = tid & 63, wid = tid >> 6;
    int wr = wid >> 1, wc = wid & 1;            // 2 x 2 wave grid

    // 8x8 grouped ordering for L2 locality: my in [0,32), nx in [0,64)
    int id = blockIdx.x, gid = id >> 6, wi = id & 63;
    int my = (gid >> 3) * 8 + (wi >> 3);
    int nx = (gid & 7) * 8 + (wi & 7);
    int b0 = my * 256, n0 = nx * 128;

    const char* mB = (const char*)msk;
    const char* bB = (const char*)bct;

    // ---- hoisted staging addresses ----
    // A panel: 256 rows x 64B; wave handles row-groups wid, wid+4, wid+8, wid+12
    // B panel: 128 rows x 64B; wave handles row-groups wid, wid+4
    // swizzle: chunk j of row r stored at phys chunk p = j ^ ((r>>1)&3)
    int rA0 = (wid +  0) * 16 + (lane >> 2);
    int rA1 = (wid +  4) * 16 + (lane >> 2);
    int rA2 = (wid +  8) * 16 + (lane >> 2);
    int rA3 = (wid + 12) * 16 + (lane >> 2);
    const char* gA0 = mB + (size_t)(b0 + rA0) * 1024 + (((lane & 3) ^ ((rA0 >> 1) & 3)) << 4);
    const char* gA1 = mB + (size_t)(b0 + rA1) * 1024 + (((lane & 3) ^ ((rA1 >> 1) & 3)) << 4);
    const char* gA2 = mB + (size_t)(b0 + rA2) * 1024 + (((lane & 3) ^ ((rA2 >> 1) & 3)) << 4);
    const char* gA3 = mB + (size_t)(b0 + rA3) * 1024 + (((lane & 3) ^ ((rA3 >> 1) & 3)) << 4);
    const char* gB0 = bB + (size_t)(n0 + rA0) * 1024 + (((lane & 3) ^ ((rA0 >> 1) & 3)) << 4);
    const char* gB1 = bB + (size_t)(n0 + rA1) * 1024 + (((lane & 3) ^ ((rA1 >> 1) & 3)) << 4);
    const int lA0o = (wid +  0) * 1024;
    const int lA1o = (wid +  4) * 1024;
    const int lA2o = (wid +  8) * 1024;
    const int lA3o = (wid + 12) * 1024;
    const int lB0o = 16384 + (wid + 0) * 1024;
    const int lB1o = 16384 + (wid + 4) * 1024;

    // ---- hoisted LDS read offsets (kk=0; kk=1 is ^32) ----
    int offA[4], offB[2];
#pragma unroll
    for (int mi = 0; mi < 4; ++mi) {
        int r = wr * 128 + mi * 32 + (lane & 31);
        offA[mi] = r * 64 + ((((lane >> 5) ^ ((r >> 1) & 3))) << 4);
    }
#pragma unroll
    for (int ni = 0; ni < 2; ++ni) {
        int r = wc * 64 + ni * 32 + (lane & 31);
        offB[ni] = 16384 + r * 64 + ((((lane >> 5) ^ ((r >> 1) & 3))) << 4);
    }

    floatx16 acc[4][2];
#pragma unroll
    for (int mi = 0; mi < 4; ++mi)
#pragma unroll
        for (int ni = 0; ni < 2; ++ni)
#pragma unroll
            for (int e = 0; e < 16; ++e) acc[mi][ni][e] = 0.f;

#define STAGE(T)                                             \
    {                                                        \
        const int bo_ = ((T) % 3) * 24576;                   \
        gl2lds16(gA0 + (T) * 64, lds + bo_ + lA0o);          \
        gl2lds16(gA1 + (T) * 64, lds + bo_ + lA1o);          \
        gl2lds16(gA2 + (T) * 64, lds + bo_ + lA2o);          \
        gl2lds16(gA3 + (T) * 64, lds + bo_ + lA3o);          \
        gl2lds16(gB0 + (T) * 64, lds + bo_ + lB0o);          \
        gl2lds16(gB1 + (T) * 64, lds + bo_ + lB1o);          \
    }

    STAGE(0); STAGE(1);     // 12 loads in flight per wave

#pragma unroll
    for (int t = 0; t < 16; ++t) {
        if (t < 15) asm volatile("s_waitcnt vmcnt(6)" ::: "memory");  // tile t landed; t+1 in flight
        else        asm volatile("s_waitcnt vmcnt(0)" ::: "memory");
        __builtin_amdgcn_s_barrier();       // tile t staged by all; buf (t-1)%3 read-complete by all
        asm volatile("" ::: "memory");
        if (t + 2 < 16) STAGE(t + 2);       // into buf (t+2)%3 == (t-1)%3

        const int bo = (t % 3) * 24576;
#pragma unroll
        for (int kk = 0; kk < 2; ++kk) {
            const int kx = kk << 5;
            f16x8 av[4], bv[2];
#pragma unroll
            for (int mi = 0; mi < 4; ++mi) av[mi] = *(const f16x8*)(lds + bo + (offA[mi] ^ kx));
#pragma unroll
            for (int ni = 0; ni < 2; ++ni) bv[ni] = *(const f16x8*)(lds + bo + (offB[ni] ^ kx));
            __builtin_amdgcn_s_setprio(1);
#pragma unroll
            for (int mi = 0; mi < 4; ++mi)
#pragma unroll
                for (int ni = 0; ni < 2; ++ni)
                    acc[mi][ni] = __builtin_amdgcn_mfma_f32_32x32x16_f16(av[mi], bv[ni], acc[mi][ni], 0, 0, 0);
            __builtin_amdgcn_s_setprio(0);
        }
    }
#undef STAGE

    __syncthreads();   // full drain before LDS reuse as epilogue scratch

    float swv[8];
#pragma unroll
    for (int m = 0; m < 8; ++m) swv[m] = wsf[m];

    // ---- epilogue: transpose each 32x32 fragment via per-wave LDS scratch ----
    // C layout: col = lane&31, row = (reg&3) + 8*(reg>>2) + 4*(lane>>5)
    float* sc = (float*)lds + wid * 1184;   // 32 rows * 36 floats + pad
    int cl = lane & 31, oh = lane >> 5;

#pragma unroll
    for (int mi = 0; mi < 4; ++mi) {
#pragma unroll
        for (int ni = 0; ni < 2; ++ni) {
#pragma unroll
            for (int reg = 0; reg < 16; ++reg) {
                int r = (reg & 3) + 8 * (reg >> 2) + 4 * oh;
                sc[r * 36 + cl] = acc[mi][ni][reg];
            }
            __asm__ volatile("s_waitcnt lgkmcnt(0)" ::: "memory");

            const float* rp = sc + cl * 36 + oh * 16;
            float4 cnA = *(const float4*)(rp + 0);
            float4 cnB = *(const float4*)(rp + 4);
            float4 cdA = *(const float4*)(rp + 8);
            float4 cdB = *(const float4*)(rp + 12);
            float cn[8] = {cnA.x, cnA.y, cnA.z, cnA.w, cnB.x, cnB.y, cnB.z, cnB.w};
            float cd[8] = {cdA.x, cdA.y, cdA.z, cdA.w, cdB.x, cdB.y, cdB.z, cdB.w};

            int b = b0 + wr * 128 + mi * 32 + cl;
            int o = ((n0 + wc * 64 + ni * 32) >> 4) + oh;
            float basev = (float)baseh[(size_t)b * FOUT + o];
            float K0 = basev + bias[o];
            bool empty = cnts[b] > 0;

            float mix = 0.f, num0 = 0.f;
#pragma unroll
            for (int m = 0; m < 8; ++m) {
                float num = K0 + cn[m];
                if (m == 0) num0 = num;
                float rs  = frsq(fmaxf(cd[m], 1e-20f));   // 1/den
                float den = cd[m] * rs;                   // sqrt(cd)
                float z   = num * rs;
                float az  = fabsf(z);
                float E   = fexp2((z * z) * -0.72134752044448170f);   // exp(-z^2/2)
                float t1  = frcp(fmaf(0.2316419f, az, 1.0f));
                float h   = fmaf(t1, 0.5307027145f, -0.7265760135f);
                h = fmaf(t1, h, 0.7107068705f);
                h = fmaf(t1, h, -0.142248368f);
                h = fmaf(t1, h, 0.127414796f);
                float u   = t1 * h;                               // Q(az)/E
                float v   = fmaf(-az, u, 0.3989422804014327f);    // (pdf - az*Q)/E
                float g   = fmaf(E, v, fmaxf(z, 0.f));            // pdf + z*cdf
                mix = fmaf(swv[m], den * g, mix);
            }
            out[(size_t)b * FOUT + o] = empty ? mix : fmaxf(num0, 0.f);
        }
    }
}

extern "C" void kernel_launch(void* const* d_in, const int* in_sizes, int n_in,
                              void* d_out, int out_size, void* d_ws, size_t ws_size,
                              hipStream_t stream) {
    const float* x        = (const float*)d_in[0];
    const float* W        = (const float*)d_in[1];
    const float* bvec     = (const float*)d_in[2];
    const float* mean_p   = (const float*)d_in[3];
    const float* log_std2 = (const float*)d_in[4];
    const float* lw       = (const float*)d_in[5];
    float* out = (float*)d_out;

    char* wsb = (char*)d_ws;
    float*     wsf  = (float*)wsb;
    int*       cnts = (int*)(wsb + WSB_CNT);
    _Float16*  base = (_Float16*)(wsb + WSB_BASE);
    _Float16*  xch  = (_Float16*)(wsb + WSB_XCH);
    _Float16*  msk  = (_Float16*)(wsb + WSB_MSK);
    _Float16*  Wh   = (_Float16*)(wsb + WSB_WH);
    _Float16*  bct  = (_Float16*)(wsb + WSB_BCT);

    prep_bct <<<B_ROWS / 4, 256, 0, stream>>>(W, mean_p, log_std2, bct, Wh);
    prep_rows<<<B_ROWS / 4, 256, 0, stream>>>(x, xch, msk, cnts, lw, wsf);
    gemm_base<<<dim3(FOUT / 64, B_ROWS / 128), 256, 0, stream>>>(xch, Wh, base);
    gmm_fused<<<(B_ROWS / 256) * (8192 / 128), 256, 0, stream>>>(msk, bct, wsf, cnts, base, bvec, out);
}

// Round 8
// 79.520 us; speedup vs baseline: 1.4828x; 1.4828x over previous
//
#include <hip/hip_runtime.h>
#include <math.h>

typedef __attribute__((ext_vector_type(8))) short short8;
typedef __attribute__((ext_vector_type(8))) _Float16 f16x8;
typedef __attribute__((ext_vector_type(4))) float floatx4;
typedef __attribute__((ext_vector_type(4))) int intx4;
typedef __attribute__((ext_vector_type(16))) int intx16;

#define B_ROWS 8192
#define FIN    512
#define FOUT   512
#define QS     4096.0f
#define QINV   0.000244140625f

// ---- workspace byte offsets ----
#define WSB_SW   0UL         // 8 floats
#define WSB_CNT  64UL        // 8192 int (any-NaN flag per row)
#define WSB_BASE 65536UL     // 8192*512 f16 base GEMM result
#define WSB_XCH  16842752UL  // 8192*512 f16 cleaned x
#define WSB_MSK  25231360UL  // 8192*512 i8 mask (1/0)
#define WSB_WH   33619968UL  // 512*512 f16 W [o][f]
#define WSB_BCT  34144256UL  // 8192*512 i8 BcT[n=o*16+t][f] quantized x4096

__device__ __forceinline__ void gl2lds16(const void* g, void* l) {
    __builtin_amdgcn_global_load_lds((const __attribute__((address_space(1))) void*)g,
                                     (__attribute__((address_space(3))) void*)l,
                                     16, 0, 0);
}

__device__ __forceinline__ float frcp(float x) { float r; asm("v_rcp_f32 %0, %1" : "=v"(r) : "v"(x)); return r; }
__device__ __forceinline__ float frsq(float x) { float r; asm("v_rsq_f32 %0, %1" : "=v"(r) : "v"(x)); return r; }
__device__ __forceinline__ float fexp2(float x){ float r; asm("v_exp_f32 %0, %1" : "=v"(r) : "v"(x)); return r; }

// ---------------- merged prep ----------------
// blocks [0,2048): BcT i8 (n=o*16+t) + Wh fold ; blocks [2048,4096): rows + softmax
__global__ __launch_bounds__(256) void prep_all(const float* __restrict__ W,
                                                const float* __restrict__ mean_p,
                                                const float* __restrict__ ls2,
                                                const float* __restrict__ x,
                                                const float* __restrict__ lw,
                                                signed char* __restrict__ bct,
                                                _Float16* __restrict__ Wh,
                                                _Float16* __restrict__ xch,
                                                signed char* __restrict__ msk,
                                                int* __restrict__ cnts,
                                                float* __restrict__ wsf) {
    int tid = threadIdx.x, lane = tid & 63, wid = tid >> 6;
    if (blockIdx.x < 2048) {
        int n  = blockIdx.x * 4 + wid;
        int fc = lane << 3;
        int o = n >> 4, t = n & 15;
        const float* wp = W + (size_t)o * FIN + fc;
        float v[8];
        if (t < 8) {
            const float* mp = mean_p + (size_t)t * FIN + fc;
#pragma unroll
            for (int j = 0; j < 8; ++j) v[j] = mp[j] * wp[j];
            if (t == 0) {
                f16x8 wv;
#pragma unroll
                for (int j = 0; j < 8; ++j) wv[j] = (_Float16)wp[j];
                *(f16x8*)(Wh + (size_t)o * FIN + fc) = wv;
            }
        } else {
            const float* lp = ls2 + (size_t)(t - 8) * FIN + fc;
#pragma unroll
            for (int j = 0; j < 8; ++j) v[j] = expf(lp[j]) * wp[j] * wp[j];
        }
        unsigned long long pack = 0;
#pragma unroll
        for (int j = 0; j < 8; ++j) {
            int q = (int)rintf(v[j] * QS);
            q = q > 127 ? 127 : (q < -127 ? -127 : q);
            pack |= ((unsigned long long)(unsigned char)(signed char)q) << (8 * j);
        }
        *(unsigned long long*)(bct + (size_t)n * FIN + fc) = pack;
    } else {
        int row = (blockIdx.x - 2048) * 4 + wid;
        const float* xr = x + (size_t)row * FIN + lane * 8;
        float4 a = *(const float4*)xr;
        float4 b = *(const float4*)(xr + 4);
        float v[8] = {a.x, a.y, a.z, a.w, b.x, b.y, b.z, b.w};
        f16x8 xo;
        unsigned long long mpack = 0;
        bool anyn = false;
#pragma unroll
        for (int j = 0; j < 8; ++j) {
            bool isn = (v[j] != v[j]);
            anyn |= isn;
            xo[j] = (_Float16)(isn ? 0.f : v[j]);
            mpack |= ((unsigned long long)(isn ? 1u : 0u)) << (8 * j);
        }
        *(f16x8*)(xch + (size_t)row * FIN + lane * 8) = xo;
        *(unsigned long long*)(msk + (size_t)row * FIN + lane * 8) = mpack;
        bool any = __any(anyn);
        if (lane == 0) cnts[row] = any ? 1 : 0;
        if (blockIdx.x == 2048 && tid == 0) {
            float mx = lw[0];
            for (int m = 1; m < 8; ++m) mx = fmaxf(mx, lw[m]);
            float e[8]; float s = 0.f;
            for (int m = 0; m < 8; ++m) { e[m] = expf(lw[m] - mx); s += e[m]; }
            for (int m = 0; m < 8; ++m) wsf[m] = e[m] / s;
        }
    }
}

// ---------------- base GEMM: base[b,o] = sum_f xch[b,f]*Wh[o,f] (f16 MFMA, f16 out) ----------------
__global__ __launch_bounds__(256) void gemm_base(const _Float16* __restrict__ xch,
                                                 const _Float16* __restrict__ Wh,
                                                 _Float16* __restrict__ base) {
    __shared__ short As[128 * 64];
    __shared__ short Bs[64 * 64];
    int tid = threadIdx.x, lane = tid & 63, wid = tid >> 6;
    int wr = wid >> 1, wc = wid & 1;
    int bb0 = blockIdx.y * 128;
    int ob0 = blockIdx.x * 64;

    floatx4 acc[4][2];
#pragma unroll
    for (int mi = 0; mi < 4; ++mi)
#pragma unroll
        for (int ni = 0; ni < 2; ++ni) acc[mi][ni] = (floatx4){0.f, 0.f, 0.f, 0.f};

    for (int ks = 0; ks < FIN; ks += 64) {
        __syncthreads();
#pragma unroll
        for (int i = 0; i < 4; ++i) {
            int cid = i * 256 + tid, row = cid >> 3, c = cid & 7;
            short8 v = *(const short8*)((const short*)xch + (((size_t)(bb0 + row)) << 9) + ks + c * 8);
            *(short8*)(&As[row * 64 + ((c ^ (row & 7)) << 3)]) = v;
        }
#pragma unroll
        for (int i = 0; i < 2; ++i) {
            int cid = i * 256 + tid, row = cid >> 3, c = cid & 7;
            short8 v = *(const short8*)((const short*)Wh + (((size_t)(ob0 + row)) << 9) + ks + c * 8);
            *(short8*)(&Bs[row * 64 + ((c ^ (row & 7)) << 3)]) = v;
        }
        __syncthreads();
#pragma unroll
        for (int kk = 0; kk < 2; ++kk) {
            f16x8 av[4], bv[2];
#pragma unroll
            for (int mi = 0; mi < 4; ++mi) {
                int row = wr * 64 + mi * 16 + (lane & 15);
                int c = kk * 4 + (lane >> 4);
                av[mi] = *(const f16x8*)(&As[row * 64 + ((c ^ (row & 7)) << 3)]);
            }
#pragma unroll
            for (int ni = 0; ni < 2; ++ni) {
                int row = wc * 32 + ni * 16 + (lane & 15);
                int c = kk * 4 + (lane >> 4);
                bv[ni] = *(const f16x8*)(&Bs[row * 64 + ((c ^ (row & 7)) << 3)]);
            }
#pragma unroll
            for (int mi = 0; mi < 4; ++mi)
#pragma unroll
                for (int ni = 0; ni < 2; ++ni)
                    acc[mi][ni] = __builtin_amdgcn_mfma_f32_16x16x32_f16(av[mi], bv[ni], acc[mi][ni], 0, 0, 0);
        }
    }
#pragma unroll
    for (int mi = 0; mi < 4; ++mi)
#pragma unroll
        for (int ni = 0; ni < 2; ++ni)
#pragma unroll
            for (int r = 0; r < 4; ++r) {
                int row = bb0 + wr * 64 + mi * 16 + (lane >> 4) * 4 + r;
                int col = ob0 + wc * 32 + ni * 16 + (lane & 15);
                base[(size_t)row * FOUT + col] = (_Float16)acc[mi][ni][r];
            }
}

// ---------------- fused mask-GEMM (i8) + epilogue ----------------
// C[b, n=o*16+t] = sum_f mask[b,f] * bct[n,f]  (i32 acc, values x4096)
// block 256(M) x 128(N), 8 waves (4m x 2n), wave tile 64x64 (2x2 frags of 32x32),
// BK=64 i8 (64B rows), 3 x 24KB LDS buffers, counted vmcnt, addressing hoisted.
__global__ __launch_bounds__(512, 4) void gmm_fused(const signed char* __restrict__ msk,
                                                    const signed char* __restrict__ bct,
                                                    const float* __restrict__ wsf,
                                                    const int* __restrict__ cnts,
                                                    const _Float16* __restrict__ baseh,
                                                    const float* __restrict__ bias,
                                                    float* __restrict__ out) {
    __shared__ char lds[73728];   // 3 x (A 16KB + B 8KB)

    int tid = threadIdx.x, lane = tid & 63, wid = tid >> 6;
    int wr = wid >> 1, wc = wid & 1;        // 4(M) x 2(N) wave grid

    // 8x8 grouped ordering for L2 locality: my in [0,32), nx in [0,64)
    int id = blockIdx.x, gid = id >> 6, wi = id & 63;
    int my = (gid >> 3) * 8 + (wi >> 3);
    int nx = (gid & 7) * 8 + (wi & 7);
    int b0 = my * 256, n0 = nx * 128;

    const char* mB = (const char*)msk;
    const char* bB = (const char*)bct;

    // ---- hoisted staging addresses (row = 512B of i8; tile = 64B slice) ----
    // A: 256 rows -> 16 groups of 16; wave handles groups wid, wid+8.
    // B: 128 rows -> 8 groups; wave handles group wid.
    int rA0 = (wid + 0) * 16 + (lane >> 2);
    int rA1 = (wid + 8) * 16 + (lane >> 2);
    int rB0 = rA0;
    const char* gA0 = mB + (size_t)(b0 + rA0) * 512 + (((lane & 3) ^ ((rA0 >> 1) & 3)) << 4);
    const char* gA1 = mB + (size_t)(b0 + rA1) * 512 + (((lane & 3) ^ ((rA1 >> 1) & 3)) << 4);
    const char* gB0 = bB + (size_t)(n0 + rB0) * 512 + (((lane & 3) ^ ((rB0 >> 1) & 3)) << 4);
    const int lA0o = (wid + 0) * 1024;
    const int lA1o = (wid + 8) * 1024;
    const int lB0o = 16384 + wid * 1024;

    // ---- hoisted LDS read offsets (kk=0; kk=1 is ^32) ----
    // frag rows: A r = wr*64 + mi*32 + (lane&31); B r = wc*64 + ni*32 + (lane&31)
    // chunk c = kk*2 + (lane>>5); phys = c ^ ((r>>1)&3)
    int offA[2], offB[2];
#pragma unroll
    for (int mi = 0; mi < 2; ++mi) {
        int r = wr * 64 + mi * 32 + (lane & 31);
        offA[mi] = r * 64 + ((((lane >> 5) ^ ((r >> 1) & 3))) << 4);
    }
#pragma unroll
    for (int ni = 0; ni < 2; ++ni) {
        int r = wc * 64 + ni * 32 + (lane & 31);
        offB[ni] = 16384 + r * 64 + ((((lane >> 5) ^ ((r >> 1) & 3))) << 4);
    }

    intx16 acc[2][2];
#pragma unroll
    for (int mi = 0; mi < 2; ++mi)
#pragma unroll
        for (int ni = 0; ni < 2; ++ni)
#pragma unroll
            for (int e = 0; e < 16; ++e) acc[mi][ni][e] = 0;

#define STAGE(T)                                             \
    {                                                        \
        const int bo_ = ((T) % 3) * 24576;                   \
        gl2lds16(gA0 + (T) * 64, lds + bo_ + lA0o);          \
        gl2lds16(gA1 + (T) * 64, lds + bo_ + lA1o);          \
        gl2lds16(gB0 + (T) * 64, lds + bo_ + lB0o);          \
    }

    STAGE(0); STAGE(1);     // 6 loads in flight per wave

#pragma unroll
    for (int t = 0; t < 8; ++t) {
        if (t < 7) asm volatile("s_waitcnt vmcnt(3)" ::: "memory");   // tile t landed; t+1 in flight
        else       asm volatile("s_waitcnt vmcnt(0)" ::: "memory");
        __builtin_amdgcn_s_barrier();       // tile t staged by all; buf (t-1)%3 read-complete by all
        asm volatile("" ::: "memory");
        if (t + 2 < 8) STAGE(t + 2);        // into buf (t+2)%3 == (t-1)%3

        const int bo = (t % 3) * 24576;
#pragma unroll
        for (int kk = 0; kk < 2; ++kk) {
            const int kx = kk << 5;
            intx4 av[2], bv[2];
#pragma unroll
            for (int mi = 0; mi < 2; ++mi) av[mi] = *(const intx4*)(lds + bo + (offA[mi] ^ kx));
#pragma unroll
            for (int ni = 0; ni < 2; ++ni) bv[ni] = *(const intx4*)(lds + bo + (offB[ni] ^ kx));
            __builtin_amdgcn_s_setprio(1);
#pragma unroll
            for (int mi = 0; mi < 2; ++mi)
#pragma unroll
                for (int ni = 0; ni < 2; ++ni)
                    acc[mi][ni] = __builtin_amdgcn_mfma_i32_32x32x32_i8(av[mi], bv[ni], acc[mi][ni], 0, 0, 0);
            __builtin_amdgcn_s_setprio(0);
        }
    }
#undef STAGE

    __syncthreads();   // full drain before LDS reuse as epilogue scratch

    float swv[8];
#pragma unroll
    for (int m = 0; m < 8; ++m) swv[m] = wsf[m];

    // ---- epilogue: transpose each 32x32 fragment via per-wave LDS scratch ----
    // C layout: col = lane&31, row = (reg&3) + 8*(reg>>2) + 4*(lane>>5)
    // scratch stride 33 dwords: writes bank (r+cl)&31, reads bank (cl+16oh+t)&31 -> conflict-free
    int* sci = (int*)lds + wid * 1056;      // 32 rows * 33 ints
    int cl = lane & 31, oh = lane >> 5;

#pragma unroll
    for (int mi = 0; mi < 2; ++mi) {
#pragma unroll
        for (int ni = 0; ni < 2; ++ni) {
#pragma unroll
            for (int reg = 0; reg < 16; ++reg) {
                int r = (reg & 3) + 8 * (reg >> 2) + 4 * oh;
                sci[r * 33 + cl] = acc[mi][ni][reg];
            }
            __asm__ volatile("s_waitcnt lgkmcnt(0)" ::: "memory");

            float cn[8], cd[8];
#pragma unroll
            for (int tt = 0; tt < 8; ++tt) cn[tt] = (float)sci[cl * 33 + oh * 16 + tt] * QINV;
#pragma unroll
            for (int tt = 0; tt < 8; ++tt) cd[tt] = (float)sci[cl * 33 + oh * 16 + 8 + tt] * QINV;

            int b = b0 + wr * 64 + mi * 32 + cl;
            int o = ((n0 + wc * 64 + ni * 32) >> 4) + oh;
            float basev = (float)baseh[(size_t)b * FOUT + o];
            float K0 = basev + bias[o];
            bool empty = cnts[b] > 0;

            float mix = 0.f, num0 = 0.f;
#pragma unroll
            for (int m = 0; m < 8; ++m) {
                float num = K0 + cn[m];
                if (m == 0) num0 = num;
                float rs  = frsq(fmaxf(cd[m], 1e-20f));   // 1/den
                float den = cd[m] * rs;                   // sqrt(cd)
                float z   = num * rs;
                float az  = fabsf(z);
                float E   = fexp2((z * z) * -0.72134752044448170f);   // exp(-z^2/2)
                float t1  = frcp(fmaf(0.2316419f, az, 1.0f));
                float h   = fmaf(t1, 0.5307027145f, -0.7265760135f);
                h = fmaf(t1, h, 0.7107068705f);
                h = fmaf(t1, h, -0.142248368f);
                h = fmaf(t1, h, 0.127414796f);
                float u   = t1 * h;                               // Q(az)/E
                float v   = fmaf(-az, u, 0.3989422804014327f);    // (pdf - az*Q)/E
                float g   = fmaf(E, v, fmaxf(z, 0.f));            // pdf + z*cdf
                mix = fmaf(swv[m], den * g, mix);
            }
            out[(size_t)b * FOUT + o] = empty ? mix : fmaxf(num0, 0.f);
        }
    }
}

extern "C" void kernel_launch(void* const* d_in, const int* in_sizes, int n_in,
                              void* d_out, int out_size, void* d_ws, size_t ws_size,
                              hipStream_t stream) {
    const float* x        = (const float*)d_in[0];
    const float* W        = (const float*)d_in[1];
    const float* bvec     = (const float*)d_in[2];
    const float* mean_p   = (const float*)d_in[3];
    const float* log_std2 = (const float*)d_in[4];
    const float* lw       = (const float*)d_in[5];
    float* out = (float*)d_out;

    char* wsb = (char*)d_ws;
    float*        wsf  = (float*)wsb;
    int*          cnts = (int*)(wsb + WSB_CNT);
    _Float16*     base = (_Float16*)(wsb + WSB_BASE);
    _Float16*     xch  = (_Float16*)(wsb + WSB_XCH);
    signed char*  msk  = (signed char*)(wsb + WSB_MSK);
    _Float16*     Wh   = (_Float16*)(wsb + WSB_WH);
    signed char*  bct  = (signed char*)(wsb + WSB_BCT);

    prep_all<<<4096, 256, 0, stream>>>(W, mean_p, log_std2, x, lw, bct, Wh, xch, msk, cnts, wsf);
    gemm_base<<<dim3(FOUT / 64, B_ROWS / 128), 256, 0, stream>>>(xch, Wh, base);
    gmm_fused<<<(B_ROWS / 256) * (8192 / 128), 512, 0, stream>>>(msk, bct, wsf, cnts, base, bvec, out);
}